// Round 3
// baseline (279.775 us; speedup 1.0000x reference)
//
#include <hip/hip_runtime.h>
#include <hip/hip_bf16.h>

#define NV 100000
#define NE 20000
#define DD 128
#define NBE 1250          // e-bucket = dst>>4 -> 16 edges per bucket
#define NBV 391           // v-bucket = src>>8 -> 256 vertices per bucket
#define NBMAX 1280
#define PBE 5             // partition scan: buckets per thread (E)
#define PBV 2             // (V)
#define CHUNK 4096
#define CAPE 1664         // per-e-bucket capacity (mean 1280, sigma ~36 -> +10.7σ)
#define CAPV 5120         // per-v-bucket capacity (mean 4096, sigma ~64 -> +16σ)

using bf16 = __hip_bfloat16;

typedef __attribute__((ext_vector_type(8))) short frag_ab;
typedef __attribute__((ext_vector_type(4))) float frag_cd;

__device__ __forceinline__ float uas(unsigned u) { union { unsigned u; float f; } c; c.u = u; return c.f; }
__device__ __forceinline__ unsigned pk2(float lo, float hi) {
    bf16 l = __float2bfloat16(lo), h = __float2bfloat16(hi);
    return (unsigned)(*(unsigned short*)&l) | ((unsigned)(*(unsigned short*)&h) << 16);
}
__device__ __forceinline__ void accum8(float* a, uint4 x) {
    a[0] += uas(x.x << 16); a[1] += uas(x.x & 0xffff0000u);
    a[2] += uas(x.y << 16); a[3] += uas(x.y & 0xffff0000u);
    a[4] += uas(x.z << 16); a[5] += uas(x.z & 0xffff0000u);
    a[6] += uas(x.w << 16); a[7] += uas(x.w & 0xffff0000u);
}
__device__ __forceinline__ int wave_incl_scan(int v, int lane) {
#pragma unroll
    for (int o = 1; o < 64; o <<= 1) {
        int x = __shfl_up(v, o);
        if (lane >= o) v += x;
    }
    return v;
}

// ---------------- init per-bucket cursors ----------------
__global__ void init_cur(int* __restrict__ bcur_e, int* __restrict__ bcur_v) {
    int t = threadIdx.x;  // 1024
    for (int i = t; i < NBE; i += 1024) bcur_e[i] = i * CAPE;
    for (int i = t; i < NBV; i += 1024) bcur_v[i] = i * CAPV;
}

// ---------------- LDS-staged radix partition (fine buckets, phase-specialized blocks) + cvt ----------------
// blocks [0, nchunk)        : phase E (bucket by dst>>4, 1250 buckets)
// blocks [nchunk, 2*nchunk) : phase V (bucket by src>>8, 391 buckets)
// blocks [2*nchunk, +ncvt)  : X/W fp32->bf16 conversion
__global__ __launch_bounds__(256) void partition_and_cvt(const int* __restrict__ src, const int* __restrict__ dst,
                                                         int* __restrict__ bcur_e, int* __restrict__ bcur_v,
                                                         unsigned* __restrict__ pairs_e, unsigned* __restrict__ pairs_v,
                                                         int nnz,
                                                         const float4* __restrict__ Xf, ushort4* __restrict__ Xb,
                                                         const float4* __restrict__ Wf, ushort4* __restrict__ Wb) {
    int nchunk = (nnz + CHUNK - 1) / CHUNK;
    int t = threadIdx.x;
    int bid = blockIdx.x;
    if (bid >= 2 * nchunk) {
        const int n4x = NV * DD / 4;
        const int n4w = DD * DD / 4;
        int i = (bid - 2 * nchunk) * 256 + t;
        if (i < n4x + n4w) {
            float4 v;
            ushort4 o;
            if (i < n4x) v = Xf[i]; else v = Wf[i - n4x];
            bf16 a = __float2bfloat16(v.x); o.x = *(unsigned short*)&a;
            bf16 b = __float2bfloat16(v.y); o.y = *(unsigned short*)&b;
            bf16 c = __float2bfloat16(v.z); o.z = *(unsigned short*)&c;
            bf16 d = __float2bfloat16(v.w); o.w = *(unsigned short*)&d;
            if (i < n4x) Xb[i] = o; else Wb[i - n4x] = o;
        }
        return;
    }
    __shared__ int cntA[NBMAX], cntB[NBMAX], loff[NBMAX], gbase[NBMAX], wsum[4];
    __shared__ int totValid;
    __shared__ unsigned stage[CHUNK];
    int phase = (bid >= nchunk) ? 1 : 0;
    int cidx = phase ? bid - nchunk : bid;
    int NB = phase ? NBV : NBE;
    int PB = phase ? PBV : PBE;
    int* cur = phase ? bcur_v : bcur_e;
    int sub = t >> 7;  // 0 or 1
    int lane = t & 63, wv = t >> 6;
    int base = cidx * CHUNK;
    unsigned p[16];
    int rk[16];
#pragma unroll
    for (int k = 0; k < 16; ++k) {
        int i = base + k * 256 + t;
        p[k] = (i < nnz) ? (((unsigned)src[i] << 15) | (unsigned)dst[i]) : 0xFFFFFFFFu;
    }

    for (int i = t; i < NBMAX; i += 256) { cntA[i] = 0; cntB[i] = 0; }
    __syncthreads();
#pragma unroll
    for (int k = 0; k < 16; ++k)
        if (p[k] != 0xFFFFFFFFu) {
            int b = phase ? (int)(p[k] >> 23) : (int)((p[k] >> 4) & 0x7FF);
            rk[k] = atomicAdd(sub ? &cntB[b] : &cntA[b], 1);
        }
    __syncthreads();
    {
        int run = 0;
        int lcl[PBE];
#pragma unroll
        for (int q = 0; q < PBE; ++q) lcl[q] = 0;
        for (int q = 0; q < PB; ++q) {
            int bkt = t * PB + q;
            int tv = (bkt < NB) ? (cntA[bkt] + cntB[bkt]) : 0;
            lcl[q] = run; run += tv;
        }
        int incl = wave_incl_scan(run, lane);
        if (lane == 63) wsum[wv] = incl;
        __syncthreads();
        if (t == 0) { int r = 0; for (int i = 0; i < 4; ++i) { int x = wsum[i]; wsum[i] = r; r += x; } }
        __syncthreads();
        int ex = incl - run + wsum[wv];
        for (int q = 0; q < PB; ++q) {
            int bkt = t * PB + q;
            if (bkt < NB) {
                int tv = cntA[bkt] + cntB[bkt];
                loff[bkt] = ex + lcl[q];
                gbase[bkt] = (tv > 0) ? atomicAdd(&cur[bkt], tv) : 0;
            }
        }
        if (t == 255) totValid = ex + run;
    }
    __syncthreads();
#pragma unroll
    for (int k = 0; k < 16; ++k)
        if (p[k] != 0xFFFFFFFFu) {
            int b = phase ? (int)(p[k] >> 23) : (int)((p[k] >> 4) & 0x7FF);
            stage[loff[b] + rk[k] + (sub ? cntA[b] : 0)] = p[k];
        }
    __syncthreads();
    unsigned* outp = phase ? pairs_v : pairs_e;
    for (int i = t; i < totValid; i += 256) {
        unsigned pp = stage[i];
        int b = phase ? (int)(pp >> 23) : (int)((pp >> 4) & 0x7FF);
        outp[gbase[b] + i - loff[b]] = pp;
    }
}

// ---------------- V-side per-bucket sort: 256 vertices/bucket, emits off_v/deg_v + ushort v_edge ----------------
__global__ __launch_bounds__(1024) void vsort(const unsigned* __restrict__ pairs_v, const int* __restrict__ bcur_v,
                                              int* __restrict__ off_v, int* __restrict__ deg_v,
                                              unsigned short* __restrict__ v_edge) {
    __shared__ int cA[1024], cB[1024], sc2[256], eoff[256], wsumS[4];
    int t = threadIdx.x;
    cA[t] = 0;
    __syncthreads();
    int b = blockIdx.x;
    int lo = b * CAPV, hi = bcur_v[b];
    int sub = t >> 8;  // 0..3 over 256 counters
    unsigned pv[5];
    int rk[5];
    int kk = 0;
    for (int i = lo + t; i < hi; i += 1024, ++kk) {
        unsigned p = pairs_v[i];
        pv[kk] = p;
        rk[kk] = atomicAdd(&cA[sub * 256 + ((p >> 15) & 255)], 1);
    }
    __syncthreads();
    if (t < 256) {
        int run = 0;
#pragma unroll
        for (int s = 0; s < 4; ++s) { cB[s * 256 + t] = run; run += cA[s * 256 + t]; }
        sc2[t] = run;
    }
    __syncthreads();
    int incl = 0, myrun = 0;
    if (t < 256) {
        myrun = sc2[t];
        incl = wave_incl_scan(myrun, t & 63);
        if ((t & 63) == 63) wsumS[t >> 6] = incl;
    }
    __syncthreads();
    if (t == 0) { int r = 0; for (int i = 0; i < 4; ++i) { int x = wsumS[i]; wsumS[i] = r; r += x; } }
    __syncthreads();
    if (t < 256) {
        int ex = incl - myrun + wsumS[t >> 6];
        eoff[t] = ex;
        int v = (b << 8) + t;
        if (v < NV) { off_v[v] = lo + ex; deg_v[v] = myrun; }
    }
    __syncthreads();
    for (int k = 0; k < kk; ++k) {
        int bkt = (pv[k] >> 15) & 255;
        int pos = lo + eoff[bkt] + cB[sub * 256 + bkt] + rk[k];
        v_edge[pos] = (unsigned short)(pv[k] & 0x7FFF);
    }
}

// ---------------- fused E-sort + edge aggregation + GEMM: bucket(16 edges) per block ----------------
// block = 256 = 4 waves = 16 groups of 16 lanes; group owns one edge; e_src list lives in LDS
__global__ __launch_bounds__(256) void edge_fused(const uint4* __restrict__ Xq, const unsigned* __restrict__ pairs_e,
                                                  const int* __restrict__ bcur_e, const int* __restrict__ deg_v,
                                                  const bf16* __restrict__ Wb, const float* __restrict__ bias,
                                                  bf16* __restrict__ Y) {
    __shared__ int cntS[64], cB16[64], cntE[16], eoffS[16];
    __shared__ int Lst[CAPE];
    __shared__ short Stile[16][136];  // 272B row stride -> 2-way aliasing only (free)
    __shared__ float betaL[16];
    int t = threadIdx.x;
    int w = t >> 6, lane = t & 63;
    int g = lane >> 4, l16 = lane & 15;
    int bkt = blockIdx.x;
    int lo = bkt * CAPE, hi = bcur_e[bkt];
    int sub = w;  // 4 replicas, one per wave

    if (t < 64) cntS[t] = 0;
    __syncthreads();
    unsigned pv[7];
    int rk[7];
    int kk = 0;
    for (int i = lo + t; i < hi; i += 256, ++kk) {
        unsigned p = pairs_e[i];
        pv[kk] = p;
        rk[kk] = atomicAdd(&cntS[sub * 16 + (p & 15)], 1);
    }
    __syncthreads();
    if (t < 16) {
        int run = 0;
#pragma unroll
        for (int s = 0; s < 4; ++s) { cB16[s * 16 + t] = run; run += cntS[s * 16 + t]; }
        cntE[t] = run;
    }
    __syncthreads();
    if (w == 0) {
        int v = (lane < 16) ? cntE[lane] : 0;
        int incl = wave_incl_scan(v, lane);
        if (lane < 16) eoffS[lane] = incl - v;
    }
    __syncthreads();
    for (int k = 0; k < kk; ++k) {
        int bb = pv[k] & 15;
        Lst[eoffS[bb] + cB16[sub * 16 + bb] + rk[k]] = (int)(pv[k] >> 15);
    }
    __syncthreads();

    // ---- gather + aggregate: group g owns edge le ----
    int mBase = bkt * 16;
    int le = t >> 4;           // 0..15  (== w*4 + g)
    int start = eoffS[le], cnt = cntE[le];
    int end = start + cnt;
    float acc[8] = {0.f, 0.f, 0.f, 0.f, 0.f, 0.f, 0.f, 0.f};
    float degsum = 0.f;
    int j = start;
    for (; j + 8 <= end; j += 8) {
        int s0 = Lst[j + 0], s1 = Lst[j + 1], s2 = Lst[j + 2], s3 = Lst[j + 3];
        int s4 = Lst[j + 4], s5 = Lst[j + 5], s6 = Lst[j + 6], s7 = Lst[j + 7];
        uint4 x0 = Xq[(size_t)s0 * 16 + l16];
        uint4 x1 = Xq[(size_t)s1 * 16 + l16];
        uint4 x2 = Xq[(size_t)s2 * 16 + l16];
        uint4 x3 = Xq[(size_t)s3 * 16 + l16];
        uint4 x4 = Xq[(size_t)s4 * 16 + l16];
        uint4 x5 = Xq[(size_t)s5 * 16 + l16];
        uint4 x6 = Xq[(size_t)s6 * 16 + l16];
        uint4 x7 = Xq[(size_t)s7 * 16 + l16];
        degsum += (float)(deg_v[s0] + deg_v[s1] + deg_v[s2] + deg_v[s3]
                        + deg_v[s4] + deg_v[s5] + deg_v[s6] + deg_v[s7]);
        accum8(acc, x0); accum8(acc, x1); accum8(acc, x2); accum8(acc, x3);
        accum8(acc, x4); accum8(acc, x5); accum8(acc, x6); accum8(acc, x7);
    }
    for (; j + 4 <= end; j += 4) {
        int s0 = Lst[j + 0], s1 = Lst[j + 1], s2 = Lst[j + 2], s3 = Lst[j + 3];
        uint4 x0 = Xq[(size_t)s0 * 16 + l16];
        uint4 x1 = Xq[(size_t)s1 * 16 + l16];
        uint4 x2 = Xq[(size_t)s2 * 16 + l16];
        uint4 x3 = Xq[(size_t)s3 * 16 + l16];
        degsum += (float)(deg_v[s0] + deg_v[s1] + deg_v[s2] + deg_v[s3]);
        accum8(acc, x0); accum8(acc, x1); accum8(acc, x2); accum8(acc, x3);
    }
    for (; j < end; ++j) {
        int s = Lst[j];
        uint4 x = Xq[(size_t)s * 16 + l16];
        degsum += (float)deg_v[s];
        accum8(acc, x);
    }
    float cntf = (float)cnt;
    float Des = degsum / (cntf + 1.0f);
    float De = (Des > 0.f) ? rsqrtf(fmaxf(Des, 1e-30f)) : 1.0f;
    float scale = De / fmaxf(cntf, 1.0f);
    {
        uint4 o;
        o.x = pk2(acc[0] * scale, acc[1] * scale);
        o.y = pk2(acc[2] * scale, acc[3] * scale);
        o.z = pk2(acc[4] * scale, acc[5] * scale);
        o.w = pk2(acc[6] * scale, acc[7] * scale);
        *(uint4*)&Stile[le][l16 * 8] = o;
        if (l16 == 0) betaL[le] = (cntf > 0.f) ? De : 0.f;
    }
    __syncthreads();

    // GEMM phase: wave w computes output column tiles nt = 2w, 2w+1
    const short* Ws = (const short*)Wb;
    int quad = g;
    frag_ab a[4];
#pragma unroll
    for (int kt = 0; kt < 4; ++kt)
        a[kt] = *(const frag_ab*)&Stile[l16][kt * 32 + quad * 8];
    float beta_r[4];
#pragma unroll
    for (int r = 0; r < 4; ++r) beta_r[r] = betaL[quad * 4 + r];

#pragma unroll
    for (int nn = 0; nn < 2; ++nn) {
        int nt = w * 2 + nn;
        frag_cd acc2 = {0.f, 0.f, 0.f, 0.f};
#pragma unroll
        for (int kt = 0; kt < 4; ++kt) {
            frag_ab bfr = *(const frag_ab*)(Ws + (size_t)(nt * 16 + l16) * DD + kt * 32 + quad * 8);
            acc2 = __builtin_amdgcn_mfma_f32_16x16x32_bf16(a[kt], bfr, acc2, 0, 0, 0);
        }
        float bv = bias[nt * 16 + l16];
#pragma unroll
        for (int r = 0; r < 4; ++r) {
            int row = mBase + quad * 4 + r;
            float v = acc2[r] + beta_r[r] * bv;
            Y[(size_t)row * DD + nt * 16 + l16] = __float2bfloat16(v);
        }
    }
}

// ---------------- vertex aggregation: group-per-vertex, x8 unroll ----------------
__global__ __launch_bounds__(256) void vertex_agg(const uint4* __restrict__ Yq, const int* __restrict__ off_v,
                                                  const int* __restrict__ deg_v,
                                                  const unsigned short* __restrict__ v_edge, float* __restrict__ out) {
    int wave = (blockIdx.x * blockDim.x + threadIdx.x) >> 6;
    int lane = threadIdx.x & 63;
    int g = lane >> 4, l16 = lane & 15;
    int v = wave * 4 + g;
    if (v >= NV) return;
    int start = off_v[v], deg = deg_v[v];
    int end = start + deg;
    float acc[8] = {0.f, 0.f, 0.f, 0.f, 0.f, 0.f, 0.f, 0.f};
    int j = start;
    for (; j + 8 <= end; j += 8) {
        int e0 = v_edge[j + 0], e1 = v_edge[j + 1], e2 = v_edge[j + 2], e3 = v_edge[j + 3];
        int e4 = v_edge[j + 4], e5 = v_edge[j + 5], e6 = v_edge[j + 6], e7 = v_edge[j + 7];
        uint4 y0 = Yq[(size_t)e0 * 16 + l16];
        uint4 y1 = Yq[(size_t)e1 * 16 + l16];
        uint4 y2 = Yq[(size_t)e2 * 16 + l16];
        uint4 y3 = Yq[(size_t)e3 * 16 + l16];
        uint4 y4 = Yq[(size_t)e4 * 16 + l16];
        uint4 y5 = Yq[(size_t)e5 * 16 + l16];
        uint4 y6 = Yq[(size_t)e6 * 16 + l16];
        uint4 y7 = Yq[(size_t)e7 * 16 + l16];
        accum8(acc, y0); accum8(acc, y1); accum8(acc, y2); accum8(acc, y3);
        accum8(acc, y4); accum8(acc, y5); accum8(acc, y6); accum8(acc, y7);
    }
    for (; j + 4 <= end; j += 4) {
        int e0 = v_edge[j + 0], e1 = v_edge[j + 1], e2 = v_edge[j + 2], e3 = v_edge[j + 3];
        uint4 y0 = Yq[(size_t)e0 * 16 + l16];
        uint4 y1 = Yq[(size_t)e1 * 16 + l16];
        uint4 y2 = Yq[(size_t)e2 * 16 + l16];
        uint4 y3 = Yq[(size_t)e3 * 16 + l16];
        accum8(acc, y0); accum8(acc, y1); accum8(acc, y2); accum8(acc, y3);
    }
    for (; j < end; ++j) {
        int e = v_edge[j];
        uint4 y = Yq[(size_t)e * 16 + l16];
        accum8(acc, y);
    }
    float dvn = (deg > 0) ? rsqrtf((float)deg) : 0.f;
    float4 o1, o2;
    o1.x = fmaxf(acc[0] * dvn, 0.f);
    o1.y = fmaxf(acc[1] * dvn, 0.f);
    o1.z = fmaxf(acc[2] * dvn, 0.f);
    o1.w = fmaxf(acc[3] * dvn, 0.f);
    o2.x = fmaxf(acc[4] * dvn, 0.f);
    o2.y = fmaxf(acc[5] * dvn, 0.f);
    o2.z = fmaxf(acc[6] * dvn, 0.f);
    o2.w = fmaxf(acc[7] * dvn, 0.f);
    float4* op = (float4*)(out + (size_t)v * DD + l16 * 8);
    op[0] = o1;
    op[1] = o2;
}

extern "C" void kernel_launch(void* const* d_in, const int* in_sizes, int n_in,
                              void* d_out, int out_size, void* d_ws, size_t ws_size,
                              hipStream_t stream) {
    const float* X = (const float*)d_in[0];
    const float* W = (const float*)d_in[1];
    const float* b = (const float*)d_in[2];
    const int* src = (const int*)d_in[3];
    const int* dst = (const int*)d_in[4];
    int nnz = in_sizes[3];

    char* ws = (char*)d_ws;
    size_t o = 0;
    auto take = [&](size_t bytes) -> char* {
        char* p = ws + o;
        o += (bytes + 255) & ~(size_t)255;
        return p;
    };
    int* bcur_e = (int*)take((size_t)NBE * 4);
    int* bcur_v = (int*)take((size_t)NBV * 4);
    int* off_v = (int*)take((size_t)NV * 4);
    int* deg_v = (int*)take((size_t)NV * 4);
    unsigned short* v_edge = (unsigned short*)take((size_t)NBV * CAPV * 2);
    unsigned* pairs_e = (unsigned*)take((size_t)NBE * CAPE * 4);
    unsigned* pairs_v = (unsigned*)take((size_t)NBV * CAPV * 4);
    bf16* Y = (bf16*)take((size_t)NE * DD * 2);
    bf16* Wb = (bf16*)take((size_t)DD * DD * 2);
    bf16* Xb = (bf16*)take((size_t)NV * DD * 2);
    (void)ws_size; (void)n_in; (void)out_size;

    int nchunk = (nnz + CHUNK - 1) / CHUNK;
    int ncvt = (NV * DD / 4 + DD * DD / 4 + 255) / 256;

    init_cur<<<1, 1024, 0, stream>>>(bcur_e, bcur_v);
    partition_and_cvt<<<2 * nchunk + ncvt, 256, 0, stream>>>(src, dst, bcur_e, bcur_v, pairs_e, pairs_v, nnz,
                                                             (const float4*)X, (ushort4*)Xb,
                                                             (const float4*)W, (ushort4*)Wb);
    vsort<<<NBV, 1024, 0, stream>>>(pairs_v, bcur_v, off_v, deg_v, v_edge);
    edge_fused<<<NBE, 256, 0, stream>>>((const uint4*)Xb, pairs_e, bcur_e, deg_v, Wb, b, Y);
    vertex_agg<<<(NV / 4 * 64) / 256, 256, 0, stream>>>((const uint4*)Y, off_v, deg_v, v_edge, (float*)d_out);
}

// Round 4
// 262.892 us; speedup vs baseline: 1.0642x; 1.0642x over previous
//
#include <hip/hip_runtime.h>
#include <hip/hip_bf16.h>

#define NV 100000
#define NE 20000
#define DD 128
#define ESHIFT 7          // e-bucket = dst>>7  -> 157 buckets
#define VSHIFT 9          // v-bucket = src>>9  -> 196 buckets
#define NBE 157
#define NBV 196
#define NBK 256
#define CHUNK 4096
#define CAPE 11264        // per-e-bucket capacity (mean 10240, sigma ~101)
#define CAPV 9216         // per-v-bucket capacity (mean 8192, sigma ~90)

using bf16 = __hip_bfloat16;

typedef __attribute__((ext_vector_type(8))) short frag_ab;
typedef __attribute__((ext_vector_type(4))) float frag_cd;

__device__ __forceinline__ float uas(unsigned u) { union { unsigned u; float f; } c; c.u = u; return c.f; }
__device__ __forceinline__ unsigned pk2(float lo, float hi) {
    bf16 l = __float2bfloat16(lo), h = __float2bfloat16(hi);
    return (unsigned)(*(unsigned short*)&l) | ((unsigned)(*(unsigned short*)&h) << 16);
}
__device__ __forceinline__ void accum8(float* a, uint4 x) {
    a[0] += uas(x.x << 16); a[1] += uas(x.x & 0xffff0000u);
    a[2] += uas(x.y << 16); a[3] += uas(x.y & 0xffff0000u);
    a[4] += uas(x.z << 16); a[5] += uas(x.z & 0xffff0000u);
    a[6] += uas(x.w << 16); a[7] += uas(x.w & 0xffff0000u);
}
__device__ __forceinline__ void accum4(float* a, uint2 x) {
    a[0] += uas(x.x << 16); a[1] += uas(x.x & 0xffff0000u);
    a[2] += uas(x.y << 16); a[3] += uas(x.y & 0xffff0000u);
}
__device__ __forceinline__ int wave_incl_scan(int v, int lane) {
#pragma unroll
    for (int o = 1; o < 64; o <<= 1) {
        int x = __shfl_up(v, o);
        if (lane >= o) v += x;
    }
    return v;
}

// ---------------- LDS-staged radix partition (phase-specialized blocks) + cvt ----------------
// blocks [0, nchunk)           : phase E (bucket by dst>>7)
// blocks [nchunk, 2*nchunk)    : phase V (bucket by src>>9)
// blocks [2*nchunk, +ncvt)     : X/W fp32->bf16 conversion
// cursors are bucket-relative (zero-init via hipMemsetAsync); absolute base = bkt*CAP added here.
__global__ __launch_bounds__(256) void partition_and_cvt(const int* __restrict__ src, const int* __restrict__ dst,
                                                         int* __restrict__ bcur_e, int* __restrict__ bcur_v,
                                                         unsigned* __restrict__ pairs_e, unsigned* __restrict__ pairs_v,
                                                         int nnz,
                                                         const float4* __restrict__ Xf, ushort4* __restrict__ Xb,
                                                         const float4* __restrict__ Wf, ushort4* __restrict__ Wb) {
    int nchunk = (nnz + CHUNK - 1) / CHUNK;
    int t = threadIdx.x;
    int bid = blockIdx.x;
    if (bid >= 2 * nchunk) {
        const int n4x = NV * DD / 4;
        const int n4w = DD * DD / 4;
        int i = (bid - 2 * nchunk) * 256 + t;
        if (i < n4x + n4w) {
            float4 v;
            ushort4 o;
            if (i < n4x) v = Xf[i]; else v = Wf[i - n4x];
            bf16 a = __float2bfloat16(v.x); o.x = *(unsigned short*)&a;
            bf16 b = __float2bfloat16(v.y); o.y = *(unsigned short*)&b;
            bf16 c = __float2bfloat16(v.z); o.z = *(unsigned short*)&c;
            bf16 d = __float2bfloat16(v.w); o.w = *(unsigned short*)&d;
            if (i < n4x) Xb[i] = o; else Wb[i - n4x] = o;
        }
        return;
    }
    __shared__ int cntA[NBK], cntB[NBK], pre1[NBK], loff[NBK], gbase[NBK], wsum[4];
    __shared__ int totValid;
    __shared__ unsigned stage[CHUNK];
    int phase = (bid >= nchunk) ? 1 : 0;
    int cidx = phase ? bid - nchunk : bid;
    int sub = t >> 7;  // 0 or 1
    int lane = t & 63, wv = t >> 6;
    int base = cidx * CHUNK;
    unsigned p[16];
    int rk[16];
#pragma unroll
    for (int k = 0; k < 16; ++k) {
        int i = base + k * 256 + t;
        p[k] = (i < nnz) ? (((unsigned)src[i] << 15) | (unsigned)dst[i]) : 0xFFFFFFFFu;
    }

    cntA[t] = 0; cntB[t] = 0;
    __syncthreads();
#pragma unroll
    for (int k = 0; k < 16; ++k)
        if (p[k] != 0xFFFFFFFFu) {
            int b = phase ? (int)(p[k] >> 24) : (int)((p[k] >> ESHIFT) & 0xFF);
            rk[k] = atomicAdd(sub ? &cntB[b] : &cntA[b], 1);
        }
    __syncthreads();
    {
        int a = cntA[t], bb = cntB[t];
        int tv = a + bb;
        pre1[t] = a;
        int incl = wave_incl_scan(tv, lane);
        if (lane == 63) wsum[wv] = incl;
        __syncthreads();
        if (t == 0) { int r = 0; for (int i = 0; i < 4; ++i) { int x = wsum[i]; wsum[i] = r; r += x; } }
        __syncthreads();
        int ex = incl - tv + wsum[wv];
        loff[t] = ex;
        int rel = (tv > 0) ? atomicAdd(phase ? &bcur_v[t] : &bcur_e[t], tv) : 0;
        gbase[t] = t * (phase ? CAPV : CAPE) + rel;
        if (t == 255) totValid = ex + tv;
    }
    __syncthreads();
#pragma unroll
    for (int k = 0; k < 16; ++k)
        if (p[k] != 0xFFFFFFFFu) {
            int b = phase ? (int)(p[k] >> 24) : (int)((p[k] >> ESHIFT) & 0xFF);
            stage[loff[b] + rk[k] + (sub ? pre1[b] : 0)] = p[k];
        }
    __syncthreads();
    unsigned* outp = phase ? pairs_v : pairs_e;
    for (int i = t; i < totValid; i += 256) {
        unsigned pp = stage[i];
        int b = phase ? (int)(pp >> 24) : (int)((pp >> ESHIFT) & 0xFF);
        outp[gbase[b] + i - loff[b]] = pp;
    }
}

// ---------------- per-bucket CSR build: split counters, wave scans, rank placement ----------------
__global__ __launch_bounds__(1024) void build_csr(const unsigned* __restrict__ pairs_e, const int* __restrict__ bcur_e,
                                                  int* __restrict__ off_e, int* __restrict__ end_e, int* __restrict__ e_src,
                                                  const unsigned* __restrict__ pairs_v, const int* __restrict__ bcur_v,
                                                  int* __restrict__ off_v, unsigned short* __restrict__ v_edge,
                                                  int* __restrict__ deg_v) {
    __shared__ int cA[2048], cB[2048], sc2[512], eoff[512], wsumS[8];
    int t = threadIdx.x;
    cA[t] = 0; cA[t + 1024] = 0;
    __syncthreads();
    if ((int)blockIdx.x < NBE) {
        int b = blockIdx.x;
        int lo = b * CAPE, hi = lo + bcur_e[b];
        int sub = t >> 7;  // 0..7 over 128 counters
        unsigned pv[12];
        int rk[12];
        int kk = 0;
        for (int i = lo + t; i < hi; i += 1024, ++kk) {
            unsigned p = pairs_e[i];
            pv[kk] = p;
            rk[kk] = atomicAdd(&cA[sub * 128 + (p & 127)], 1);
        }
        __syncthreads();
        if (t < 128) {
            int run = 0;
#pragma unroll
            for (int s = 0; s < 8; ++s) { cB[s * 128 + t] = run; run += cA[s * 128 + t]; }
            sc2[t] = run;
        }
        __syncthreads();
        int incl = 0, myrun = 0;
        if (t < 128) {
            myrun = sc2[t];
            incl = wave_incl_scan(myrun, t & 63);
            if ((t & 63) == 63) wsumS[t >> 6] = incl;
        }
        __syncthreads();
        if (t == 0) { int r = 0; for (int i = 0; i < 2; ++i) { int x = wsumS[i]; wsumS[i] = r; r += x; } }
        __syncthreads();
        if (t < 128) {
            int ex = incl - myrun + wsumS[t >> 6];
            eoff[t] = ex;
            int e = (b << ESHIFT) + t;
            if (e < NE) { off_e[e] = lo + ex; end_e[e] = lo + ex + myrun; }
        }
        __syncthreads();
        for (int k = 0; k < kk; ++k) {
            int bkt = pv[k] & 127;
            int pos = lo + eoff[bkt] + cB[sub * 128 + bkt] + rk[k];
            e_src[pos] = (int)(pv[k] >> 15);
        }
    } else {
        int b = blockIdx.x - NBE;
        int lo = b * CAPV, hi = lo + bcur_v[b];
        int sub = t >> 8;  // 0..3 over 512 counters
        unsigned pv[9];
        int rk[9];
        int kk = 0;
        for (int i = lo + t; i < hi; i += 1024, ++kk) {
            unsigned p = pairs_v[i];
            pv[kk] = p;
            rk[kk] = atomicAdd(&cA[sub * 512 + ((p >> 15) & 511)], 1);
        }
        __syncthreads();
        if (t < 512) {
            int run = 0;
#pragma unroll
            for (int s = 0; s < 4; ++s) { cB[s * 512 + t] = run; run += cA[s * 512 + t]; }
            sc2[t] = run;
        }
        __syncthreads();
        int incl = 0, myrun = 0;
        if (t < 512) {
            myrun = sc2[t];
            incl = wave_incl_scan(myrun, t & 63);
            if ((t & 63) == 63) wsumS[t >> 6] = incl;
        }
        __syncthreads();
        if (t == 0) { int r = 0; for (int i = 0; i < 8; ++i) { int x = wsumS[i]; wsumS[i] = r; r += x; } }
        __syncthreads();
        if (t < 512) {
            int ex = incl - myrun + wsumS[t >> 6];
            eoff[t] = ex;
            int v = (b << VSHIFT) + t;
            if (v < NV) { off_v[v] = lo + ex; deg_v[v] = myrun; }
        }
        __syncthreads();
        for (int k = 0; k < kk; ++k) {
            int bkt = (pv[k] >> 15) & 511;
            int pos = lo + eoff[bkt] + cB[sub * 512 + bkt] + rk[k];
            v_edge[pos] = (unsigned short)(pv[k] & 0x7FFF);
        }
    }
}

// ---------------- fused edge aggregation + GEMM: two half-groups per edge, 512 threads ----------------
// (verified pattern-bound at 67 us across 3 variants -- kept byte-identical to R2)
__global__ __launch_bounds__(512) void edge_fused(const uint4* __restrict__ Xq, const int* __restrict__ off_e,
                                                  const int* __restrict__ end_e,
                                                  const int* __restrict__ e_src, const int* __restrict__ deg_v,
                                                  const bf16* __restrict__ Wb, const float* __restrict__ bias,
                                                  bf16* __restrict__ Y) {
    __shared__ short Stile[16][136];  // 272B row stride -> 2-way aliasing only (free)
    __shared__ float betaL[16];
    int t = threadIdx.x;
    int w = t >> 6, lane = t & 63;
    int h = lane >> 5;           // which half of the edge's source list
    int g2 = (lane >> 4) & 1;    // which of the wave's 2 edges
    int l16 = lane & 15;
    int mBase = blockIdx.x * 16;
    int le = w * 2 + g2;
    int e = mBase + le;
    int start = off_e[e], end = end_e[e];
    int cnt = end - start;
    int half0 = (cnt + 1) >> 1;
    int hs = start + h * half0;
    int he = h ? end : (start + half0);
    float acc[8] = {0.f, 0.f, 0.f, 0.f, 0.f, 0.f, 0.f, 0.f};
    float degsum = 0.f;
    int j = hs;
    for (; j + 8 <= he; j += 8) {
        int s0 = e_src[j + 0], s1 = e_src[j + 1], s2 = e_src[j + 2], s3 = e_src[j + 3];
        int s4 = e_src[j + 4], s5 = e_src[j + 5], s6 = e_src[j + 6], s7 = e_src[j + 7];
        uint4 x0 = Xq[(size_t)s0 * 16 + l16];
        uint4 x1 = Xq[(size_t)s1 * 16 + l16];
        uint4 x2 = Xq[(size_t)s2 * 16 + l16];
        uint4 x3 = Xq[(size_t)s3 * 16 + l16];
        uint4 x4 = Xq[(size_t)s4 * 16 + l16];
        uint4 x5 = Xq[(size_t)s5 * 16 + l16];
        uint4 x6 = Xq[(size_t)s6 * 16 + l16];
        uint4 x7 = Xq[(size_t)s7 * 16 + l16];
        degsum += (float)(deg_v[s0] + deg_v[s1] + deg_v[s2] + deg_v[s3]
                        + deg_v[s4] + deg_v[s5] + deg_v[s6] + deg_v[s7]);
        accum8(acc, x0); accum8(acc, x1); accum8(acc, x2); accum8(acc, x3);
        accum8(acc, x4); accum8(acc, x5); accum8(acc, x6); accum8(acc, x7);
    }
    for (; j + 4 <= he; j += 4) {
        int s0 = e_src[j + 0], s1 = e_src[j + 1], s2 = e_src[j + 2], s3 = e_src[j + 3];
        uint4 x0 = Xq[(size_t)s0 * 16 + l16];
        uint4 x1 = Xq[(size_t)s1 * 16 + l16];
        uint4 x2 = Xq[(size_t)s2 * 16 + l16];
        uint4 x3 = Xq[(size_t)s3 * 16 + l16];
        degsum += (float)(deg_v[s0] + deg_v[s1] + deg_v[s2] + deg_v[s3]);
        accum8(acc, x0); accum8(acc, x1); accum8(acc, x2); accum8(acc, x3);
    }
    for (; j < he; ++j) {
        int s = e_src[j];
        uint4 x = Xq[(size_t)s * 16 + l16];
        degsum += (float)deg_v[s];
        accum8(acc, x);
    }
    // merge the two halves (lanes l <-> l^32)
#pragma unroll
    for (int r = 0; r < 8; ++r) acc[r] += __shfl_xor(acc[r], 32);
    degsum += __shfl_xor(degsum, 32);

    float cntf = (float)cnt;
    float Des = degsum / (cntf + 1.0f);
    float De = (Des > 0.f) ? rsqrtf(fmaxf(Des, 1e-30f)) : 1.0f;
    float scale = De / fmaxf(cntf, 1.0f);
    if (h == 0) {
        uint4 o;
        o.x = pk2(acc[0] * scale, acc[1] * scale);
        o.y = pk2(acc[2] * scale, acc[3] * scale);
        o.z = pk2(acc[4] * scale, acc[5] * scale);
        o.w = pk2(acc[6] * scale, acc[7] * scale);
        *(uint4*)&Stile[le][l16 * 8] = o;
        if (l16 == 0) betaL[le] = (cntf > 0.f) ? De : 0.f;
    }
    __syncthreads();

    // GEMM phase: wave w computes output column tile nt = w (8 waves x 1 tile = 128 cols)
    const short* Ws = (const short*)Wb;
    int quad = lane >> 4;  // 0..3
    frag_ab a[4];
#pragma unroll
    for (int kt = 0; kt < 4; ++kt)
        a[kt] = *(const frag_ab*)&Stile[l16][kt * 32 + quad * 8];
    float beta_r[4];
#pragma unroll
    for (int r = 0; r < 4; ++r) beta_r[r] = betaL[quad * 4 + r];

    int nt = w;
    frag_cd acc2 = {0.f, 0.f, 0.f, 0.f};
#pragma unroll
    for (int kt = 0; kt < 4; ++kt) {
        frag_ab bfr = *(const frag_ab*)(Ws + (size_t)(nt * 16 + l16) * DD + kt * 32 + quad * 8);
        acc2 = __builtin_amdgcn_mfma_f32_16x16x32_bf16(a[kt], bfr, acc2, 0, 0, 0);
    }
    float bv = bias[nt * 16 + l16];
#pragma unroll
    for (int r = 0; r < 4; ++r) {
        int row = mBase + quad * 4 + r;
        float v = acc2[r] + beta_r[r] * bv;
        Y[(size_t)row * DD + nt * 16 + l16] = __float2bfloat16(v);
    }
}

// ---------------- vertex aggregation: column-half pass, group-per-vertex ----------------
// Each pass gathers only 64 of 128 Y columns: working set 2.56 MB -> fits per-XCD L2 (4 MiB).
__global__ __launch_bounds__(256) void vertex_agg(const uint2* __restrict__ Yq, const int* __restrict__ off_v,
                                                  const int* __restrict__ deg_v,
                                                  const unsigned short* __restrict__ v_edge, float* __restrict__ out,
                                                  int half) {
    int wave = (blockIdx.x * blockDim.x + threadIdx.x) >> 6;
    int lane = threadIdx.x & 63;
    int g = lane >> 4, l16 = lane & 15;
    int v = wave * 4 + g;
    if (v >= NV) return;
    int start = off_v[v], deg = deg_v[v];
    int end = start + deg;
    const uint2* Yh = Yq + half * 16 + l16;  // fixed in-row offset; row stride 32 uint2
    float acc[4] = {0.f, 0.f, 0.f, 0.f};
    int j = start;
    for (; j + 8 <= end; j += 8) {
        int e0 = v_edge[j + 0], e1 = v_edge[j + 1], e2 = v_edge[j + 2], e3 = v_edge[j + 3];
        int e4 = v_edge[j + 4], e5 = v_edge[j + 5], e6 = v_edge[j + 6], e7 = v_edge[j + 7];
        uint2 y0 = Yh[(size_t)e0 * 32];
        uint2 y1 = Yh[(size_t)e1 * 32];
        uint2 y2 = Yh[(size_t)e2 * 32];
        uint2 y3 = Yh[(size_t)e3 * 32];
        uint2 y4 = Yh[(size_t)e4 * 32];
        uint2 y5 = Yh[(size_t)e5 * 32];
        uint2 y6 = Yh[(size_t)e6 * 32];
        uint2 y7 = Yh[(size_t)e7 * 32];
        accum4(acc, y0); accum4(acc, y1); accum4(acc, y2); accum4(acc, y3);
        accum4(acc, y4); accum4(acc, y5); accum4(acc, y6); accum4(acc, y7);
    }
    for (; j + 4 <= end; j += 4) {
        int e0 = v_edge[j + 0], e1 = v_edge[j + 1], e2 = v_edge[j + 2], e3 = v_edge[j + 3];
        uint2 y0 = Yh[(size_t)e0 * 32];
        uint2 y1 = Yh[(size_t)e1 * 32];
        uint2 y2 = Yh[(size_t)e2 * 32];
        uint2 y3 = Yh[(size_t)e3 * 32];
        accum4(acc, y0); accum4(acc, y1); accum4(acc, y2); accum4(acc, y3);
    }
    for (; j < end; ++j) {
        int e = v_edge[j];
        uint2 y = Yh[(size_t)e * 32];
        accum4(acc, y);
    }
    float dvn = (deg > 0) ? rsqrtf((float)deg) : 0.f;
    float4 o1;
    o1.x = fmaxf(acc[0] * dvn, 0.f);
    o1.y = fmaxf(acc[1] * dvn, 0.f);
    o1.z = fmaxf(acc[2] * dvn, 0.f);
    o1.w = fmaxf(acc[3] * dvn, 0.f);
    *(float4*)(out + (size_t)v * DD + half * 64 + l16 * 4) = o1;
}

extern "C" void kernel_launch(void* const* d_in, const int* in_sizes, int n_in,
                              void* d_out, int out_size, void* d_ws, size_t ws_size,
                              hipStream_t stream) {
    const float* X = (const float*)d_in[0];
    const float* W = (const float*)d_in[1];
    const float* b = (const float*)d_in[2];
    const int* src = (const int*)d_in[3];
    const int* dst = (const int*)d_in[4];
    int nnz = in_sizes[3];

    char* ws = (char*)d_ws;
    size_t o = 0;
    auto take = [&](size_t bytes) -> char* {
        char* p = ws + o;
        o += (bytes + 255) & ~(size_t)255;
        return p;
    };
    int* bcur_e = (int*)take((size_t)2 * NBK * 4);  // bcur_v contiguous
    int* bcur_v = bcur_e + NBK;
    int* off_e = (int*)take((size_t)NE * 4);
    int* end_e = (int*)take((size_t)NE * 4);
    int* off_v = (int*)take((size_t)NV * 4);
    int* deg_v = (int*)take((size_t)NV * 4);
    int* e_src = (int*)take((size_t)NBE * CAPE * 4);
    unsigned short* v_edge = (unsigned short*)take((size_t)NBV * CAPV * 2);
    unsigned* pairs_e = (unsigned*)take((size_t)NBE * CAPE * 4);
    unsigned* pairs_v = (unsigned*)take((size_t)NBV * CAPV * 4);
    bf16* Y = (bf16*)take((size_t)NE * DD * 2);
    bf16* Wb = (bf16*)take((size_t)DD * DD * 2);
    bf16* Xb = (bf16*)take((size_t)NV * DD * 2);
    (void)ws_size; (void)n_in; (void)out_size;

    int nchunk = (nnz + CHUNK - 1) / CHUNK;
    int ncvt = (NV * DD / 4 + DD * DD / 4 + 255) / 256;

    hipMemsetAsync(bcur_e, 0, (size_t)2 * NBK * 4, stream);
    partition_and_cvt<<<2 * nchunk + ncvt, 256, 0, stream>>>(src, dst, bcur_e, bcur_v, pairs_e, pairs_v, nnz,
                                                             (const float4*)X, (ushort4*)Xb,
                                                             (const float4*)W, (ushort4*)Wb);
    build_csr<<<NBE + NBV, 1024, 0, stream>>>(pairs_e, bcur_e, off_e, end_e, e_src,
                                              pairs_v, bcur_v, off_v, v_edge, deg_v);
    edge_fused<<<NE / 16, 512, 0, stream>>>((const uint4*)Xb, off_e, end_e, e_src, deg_v, Wb, b, Y);
    vertex_agg<<<NV / 16, 256, 0, stream>>>((const uint2*)Y, off_v, deg_v, v_edge, (float*)d_out, 0);
    vertex_agg<<<NV / 16, 256, 0, stream>>>((const uint2*)Y, off_v, deg_v, v_edge, (float*)d_out, 1);
}

// Round 5
// 241.136 us; speedup vs baseline: 1.1602x; 1.0902x over previous
//
#include <hip/hip_runtime.h>
#include <hip/hip_bf16.h>

#define NV 100000
#define NE 20000
#define DD 128
#define ESHIFT 7          // e-bucket = dst>>7  -> 157 buckets
#define VSHIFT 9          // v-bucket = src>>9  -> 196 buckets
#define NBE 157
#define NBV 196
#define NBK 256
#define CHUNK 8192        // flush runs avg 32 u32 = 128B -> full-line writes
#define PTHREADS 512
#define CAPE 11264        // per-e-bucket capacity (mean 10191, sigma ~100)
#define CAPV 9216         // per-v-bucket capacity (mean 8163, sigma ~90)

using bf16 = __hip_bfloat16;

typedef __attribute__((ext_vector_type(8))) short frag_ab;
typedef __attribute__((ext_vector_type(4))) float frag_cd;

__device__ __forceinline__ float uas(unsigned u) { union { unsigned u; float f; } c; c.u = u; return c.f; }
__device__ __forceinline__ unsigned pk2(float lo, float hi) {
    bf16 l = __float2bfloat16(lo), h = __float2bfloat16(hi);
    return (unsigned)(*(unsigned short*)&l) | ((unsigned)(*(unsigned short*)&h) << 16);
}
__device__ __forceinline__ void accum8(float* a, uint4 x) {
    a[0] += uas(x.x << 16); a[1] += uas(x.x & 0xffff0000u);
    a[2] += uas(x.y << 16); a[3] += uas(x.y & 0xffff0000u);
    a[4] += uas(x.z << 16); a[5] += uas(x.z & 0xffff0000u);
    a[6] += uas(x.w << 16); a[7] += uas(x.w & 0xffff0000u);
}
__device__ __forceinline__ int wave_incl_scan(int v, int lane) {
#pragma unroll
    for (int o = 1; o < 64; o <<= 1) {
        int x = __shfl_up(v, o);
        if (lane >= o) v += x;
    }
    return v;
}

// ---------------- LDS-staged radix partition (phase-specialized blocks, CHUNK=8192/512t) + cvt ----------------
// blocks [0, nchunk)           : phase E (bucket by dst>>7)
// blocks [nchunk, 2*nchunk)    : phase V (bucket by src>>9)
// blocks [2*nchunk, +ncvt)     : X/W fp32->bf16 conversion
// cursors are bucket-relative (zero-init via hipMemsetAsync); absolute base = bkt*CAP added here.
__global__ __launch_bounds__(PTHREADS) void partition_and_cvt(const int* __restrict__ src, const int* __restrict__ dst,
                                                              int* __restrict__ bcur_e, int* __restrict__ bcur_v,
                                                              unsigned* __restrict__ pairs_e, unsigned* __restrict__ pairs_v,
                                                              int nnz,
                                                              const float4* __restrict__ Xf, ushort4* __restrict__ Xb,
                                                              const float4* __restrict__ Wf, ushort4* __restrict__ Wb) {
    int nchunk = (nnz + CHUNK - 1) / CHUNK;
    int t = threadIdx.x;
    int bid = blockIdx.x;
    if (bid >= 2 * nchunk) {
        const int n4x = NV * DD / 4;
        const int n4w = DD * DD / 4;
        int i = (bid - 2 * nchunk) * PTHREADS + t;
        if (i < n4x + n4w) {
            float4 v;
            ushort4 o;
            if (i < n4x) v = Xf[i]; else v = Wf[i - n4x];
            bf16 a = __float2bfloat16(v.x); o.x = *(unsigned short*)&a;
            bf16 b = __float2bfloat16(v.y); o.y = *(unsigned short*)&b;
            bf16 c = __float2bfloat16(v.z); o.z = *(unsigned short*)&c;
            bf16 d = __float2bfloat16(v.w); o.w = *(unsigned short*)&d;
            if (i < n4x) Xb[i] = o; else Wb[i - n4x] = o;
        }
        return;
    }
    __shared__ int cntA[NBK], cntB[NBK], pre1[NBK], loff[NBK], gbase[NBK], wsum[4];
    __shared__ int totValid;
    __shared__ unsigned stage[CHUNK];
    int phase = (bid >= nchunk) ? 1 : 0;
    int cidx = phase ? bid - nchunk : bid;
    int sub = t >> 8;  // 0 or 1 (counter replica per 256-thread half)
    int lane = t & 63;
    int base = cidx * CHUNK;
    unsigned p[16];
    int rk[16];
#pragma unroll
    for (int k = 0; k < 16; ++k) {
        int i = base + k * PTHREADS + t;
        p[k] = (i < nnz) ? (((unsigned)src[i] << 15) | (unsigned)dst[i]) : 0xFFFFFFFFu;
    }

    if (t < NBK) { cntA[t] = 0; cntB[t] = 0; }
    __syncthreads();
#pragma unroll
    for (int k = 0; k < 16; ++k)
        if (p[k] != 0xFFFFFFFFu) {
            int b = phase ? (int)(p[k] >> 24) : (int)((p[k] >> ESHIFT) & 0xFF);
            rk[k] = atomicAdd(sub ? &cntB[b] : &cntA[b], 1);
        }
    __syncthreads();
    {
        int incl = 0, tv = 0;
        if (t < NBK) {
            int a = cntA[t], bb = cntB[t];
            tv = a + bb;
            pre1[t] = a;
            incl = wave_incl_scan(tv, lane);
            if (lane == 63) wsum[t >> 6] = incl;
        }
        __syncthreads();
        if (t == 0) { int r = 0; for (int i = 0; i < 4; ++i) { int x = wsum[i]; wsum[i] = r; r += x; } }
        __syncthreads();
        if (t < NBK) {
            int ex = incl - tv + wsum[t >> 6];
            loff[t] = ex;
            int rel = (tv > 0) ? atomicAdd(phase ? &bcur_v[t] : &bcur_e[t], tv) : 0;
            gbase[t] = t * (phase ? CAPV : CAPE) + rel;
            if (t == NBK - 1) totValid = ex + tv;
        }
    }
    __syncthreads();
#pragma unroll
    for (int k = 0; k < 16; ++k)
        if (p[k] != 0xFFFFFFFFu) {
            int b = phase ? (int)(p[k] >> 24) : (int)((p[k] >> ESHIFT) & 0xFF);
            stage[loff[b] + rk[k] + (sub ? pre1[b] : 0)] = p[k];
        }
    __syncthreads();
    unsigned* outp = phase ? pairs_v : pairs_e;
    for (int i = t; i < totValid; i += PTHREADS) {
        unsigned pp = stage[i];
        int b = phase ? (int)(pp >> 24) : (int)((pp >> ESHIFT) & 0xFF);
        outp[gbase[b] + i - loff[b]] = pp;
    }
}

// ---------------- per-bucket CSR build: split counters, wave scans, rank placement ----------------
__global__ __launch_bounds__(1024) void build_csr(const unsigned* __restrict__ pairs_e, const int* __restrict__ bcur_e,
                                                  int* __restrict__ off_e, int* __restrict__ end_e, int* __restrict__ e_src,
                                                  const unsigned* __restrict__ pairs_v, const int* __restrict__ bcur_v,
                                                  int* __restrict__ off_v, unsigned short* __restrict__ v_edge,
                                                  int* __restrict__ deg_v) {
    __shared__ int cA[2048], cB[2048], sc2[512], eoff[512], wsumS[8];
    int t = threadIdx.x;
    cA[t] = 0; cA[t + 1024] = 0;
    __syncthreads();
    if ((int)blockIdx.x < NBE) {
        int b = blockIdx.x;
        int lo = b * CAPE, hi = lo + bcur_e[b];
        int sub = t >> 7;  // 0..7 over 128 counters
        unsigned pv[12];
        int rk[12];
        int kk = 0;
        for (int i = lo + t; i < hi; i += 1024, ++kk) {
            unsigned p = pairs_e[i];
            pv[kk] = p;
            rk[kk] = atomicAdd(&cA[sub * 128 + (p & 127)], 1);
        }
        __syncthreads();
        if (t < 128) {
            int run = 0;
#pragma unroll
            for (int s = 0; s < 8; ++s) { cB[s * 128 + t] = run; run += cA[s * 128 + t]; }
            sc2[t] = run;
        }
        __syncthreads();
        int incl = 0, myrun = 0;
        if (t < 128) {
            myrun = sc2[t];
            incl = wave_incl_scan(myrun, t & 63);
            if ((t & 63) == 63) wsumS[t >> 6] = incl;
        }
        __syncthreads();
        if (t == 0) { int r = 0; for (int i = 0; i < 2; ++i) { int x = wsumS[i]; wsumS[i] = r; r += x; } }
        __syncthreads();
        if (t < 128) {
            int ex = incl - myrun + wsumS[t >> 6];
            eoff[t] = ex;
            int e = (b << ESHIFT) + t;
            if (e < NE) { off_e[e] = lo + ex; end_e[e] = lo + ex + myrun; }
        }
        __syncthreads();
        for (int k = 0; k < kk; ++k) {
            int bkt = pv[k] & 127;
            int pos = lo + eoff[bkt] + cB[sub * 128 + bkt] + rk[k];
            e_src[pos] = (int)(pv[k] >> 15);
        }
    } else {
        int b = blockIdx.x - NBE;
        int lo = b * CAPV, hi = lo + bcur_v[b];
        int sub = t >> 8;  // 0..3 over 512 counters
        unsigned pv[9];
        int rk[9];
        int kk = 0;
        for (int i = lo + t; i < hi; i += 1024, ++kk) {
            unsigned p = pairs_v[i];
            pv[kk] = p;
            rk[kk] = atomicAdd(&cA[sub * 512 + ((p >> 15) & 511)], 1);
        }
        __syncthreads();
        if (t < 512) {
            int run = 0;
#pragma unroll
            for (int s = 0; s < 4; ++s) { cB[s * 512 + t] = run; run += cA[s * 512 + t]; }
            sc2[t] = run;
        }
        __syncthreads();
        int incl = 0, myrun = 0;
        if (t < 512) {
            myrun = sc2[t];
            incl = wave_incl_scan(myrun, t & 63);
            if ((t & 63) == 63) wsumS[t >> 6] = incl;
        }
        __syncthreads();
        if (t == 0) { int r = 0; for (int i = 0; i < 8; ++i) { int x = wsumS[i]; wsumS[i] = r; r += x; } }
        __syncthreads();
        if (t < 512) {
            int ex = incl - myrun + wsumS[t >> 6];
            eoff[t] = ex;
            int v = (b << VSHIFT) + t;
            if (v < NV) { off_v[v] = lo + ex; deg_v[v] = myrun; }
        }
        __syncthreads();
        for (int k = 0; k < kk; ++k) {
            int bkt = (pv[k] >> 15) & 511;
            int pos = lo + eoff[bkt] + cB[sub * 512 + bkt] + rk[k];
            v_edge[pos] = (unsigned short)(pv[k] & 0x7FFF);
        }
    }
}

// ---------------- fused edge aggregation + GEMM: two half-groups per edge, 512 threads ----------------
// (verified pattern-bound at 65-67 us across 4 variants -- kept byte-identical to R2)
__global__ __launch_bounds__(512) void edge_fused(const uint4* __restrict__ Xq, const int* __restrict__ off_e,
                                                  const int* __restrict__ end_e,
                                                  const int* __restrict__ e_src, const int* __restrict__ deg_v,
                                                  const bf16* __restrict__ Wb, const float* __restrict__ bias,
                                                  bf16* __restrict__ Y) {
    __shared__ short Stile[16][136];  // 272B row stride -> 2-way aliasing only (free)
    __shared__ float betaL[16];
    int t = threadIdx.x;
    int w = t >> 6, lane = t & 63;
    int h = lane >> 5;           // which half of the edge's source list
    int g2 = (lane >> 4) & 1;    // which of the wave's 2 edges
    int l16 = lane & 15;
    int mBase = blockIdx.x * 16;
    int le = w * 2 + g2;
    int e = mBase + le;
    int start = off_e[e], end = end_e[e];
    int cnt = end - start;
    int half0 = (cnt + 1) >> 1;
    int hs = start + h * half0;
    int he = h ? end : (start + half0);
    float acc[8] = {0.f, 0.f, 0.f, 0.f, 0.f, 0.f, 0.f, 0.f};
    float degsum = 0.f;
    int j = hs;
    for (; j + 8 <= he; j += 8) {
        int s0 = e_src[j + 0], s1 = e_src[j + 1], s2 = e_src[j + 2], s3 = e_src[j + 3];
        int s4 = e_src[j + 4], s5 = e_src[j + 5], s6 = e_src[j + 6], s7 = e_src[j + 7];
        uint4 x0 = Xq[(size_t)s0 * 16 + l16];
        uint4 x1 = Xq[(size_t)s1 * 16 + l16];
        uint4 x2 = Xq[(size_t)s2 * 16 + l16];
        uint4 x3 = Xq[(size_t)s3 * 16 + l16];
        uint4 x4 = Xq[(size_t)s4 * 16 + l16];
        uint4 x5 = Xq[(size_t)s5 * 16 + l16];
        uint4 x6 = Xq[(size_t)s6 * 16 + l16];
        uint4 x7 = Xq[(size_t)s7 * 16 + l16];
        degsum += (float)(deg_v[s0] + deg_v[s1] + deg_v[s2] + deg_v[s3]
                        + deg_v[s4] + deg_v[s5] + deg_v[s6] + deg_v[s7]);
        accum8(acc, x0); accum8(acc, x1); accum8(acc, x2); accum8(acc, x3);
        accum8(acc, x4); accum8(acc, x5); accum8(acc, x6); accum8(acc, x7);
    }
    for (; j + 4 <= he; j += 4) {
        int s0 = e_src[j + 0], s1 = e_src[j + 1], s2 = e_src[j + 2], s3 = e_src[j + 3];
        uint4 x0 = Xq[(size_t)s0 * 16 + l16];
        uint4 x1 = Xq[(size_t)s1 * 16 + l16];
        uint4 x2 = Xq[(size_t)s2 * 16 + l16];
        uint4 x3 = Xq[(size_t)s3 * 16 + l16];
        degsum += (float)(deg_v[s0] + deg_v[s1] + deg_v[s2] + deg_v[s3]);
        accum8(acc, x0); accum8(acc, x1); accum8(acc, x2); accum8(acc, x3);
    }
    for (; j < he; ++j) {
        int s = e_src[j];
        uint4 x = Xq[(size_t)s * 16 + l16];
        degsum += (float)deg_v[s];
        accum8(acc, x);
    }
    // merge the two halves (lanes l <-> l^32)
#pragma unroll
    for (int r = 0; r < 8; ++r) acc[r] += __shfl_xor(acc[r], 32);
    degsum += __shfl_xor(degsum, 32);

    float cntf = (float)cnt;
    float Des = degsum / (cntf + 1.0f);
    float De = (Des > 0.f) ? rsqrtf(fmaxf(Des, 1e-30f)) : 1.0f;
    float scale = De / fmaxf(cntf, 1.0f);
    if (h == 0) {
        uint4 o;
        o.x = pk2(acc[0] * scale, acc[1] * scale);
        o.y = pk2(acc[2] * scale, acc[3] * scale);
        o.z = pk2(acc[4] * scale, acc[5] * scale);
        o.w = pk2(acc[6] * scale, acc[7] * scale);
        *(uint4*)&Stile[le][l16 * 8] = o;
        if (l16 == 0) betaL[le] = (cntf > 0.f) ? De : 0.f;
    }
    __syncthreads();

    // GEMM phase: wave w computes output column tile nt = w (8 waves x 1 tile = 128 cols)
    const short* Ws = (const short*)Wb;
    int quad = lane >> 4;  // 0..3
    frag_ab a[4];
#pragma unroll
    for (int kt = 0; kt < 4; ++kt)
        a[kt] = *(const frag_ab*)&Stile[l16][kt * 32 + quad * 8];
    float beta_r[4];
#pragma unroll
    for (int r = 0; r < 4; ++r) beta_r[r] = betaL[quad * 4 + r];

    int nt = w;
    frag_cd acc2 = {0.f, 0.f, 0.f, 0.f};
#pragma unroll
    for (int kt = 0; kt < 4; ++kt) {
        frag_ab bfr = *(const frag_ab*)(Ws + (size_t)(nt * 16 + l16) * DD + kt * 32 + quad * 8);
        acc2 = __builtin_amdgcn_mfma_f32_16x16x32_bf16(a[kt], bfr, acc2, 0, 0, 0);
    }
    float bv = bias[nt * 16 + l16];
#pragma unroll
    for (int r = 0; r < 4; ++r) {
        int row = mBase + quad * 4 + r;
        float v = acc2[r] + beta_r[r] * bv;
        Y[(size_t)row * DD + nt * 16 + l16] = __float2bfloat16(v);
    }
}

// ---------------- vertex aggregation: single-pass group-per-vertex, uint4 gathers (R2-verified form) ----------------
__global__ __launch_bounds__(256) void vertex_agg(const uint4* __restrict__ Yq, const int* __restrict__ off_v,
                                                  const int* __restrict__ deg_v,
                                                  const unsigned short* __restrict__ v_edge, float* __restrict__ out) {
    int wave = (blockIdx.x * blockDim.x + threadIdx.x) >> 6;
    int lane = threadIdx.x & 63;
    int g = lane >> 4, l16 = lane & 15;
    int v = wave * 4 + g;
    if (v >= NV) return;
    int start = off_v[v], deg = deg_v[v];
    int end = start + deg;
    float acc[8] = {0.f, 0.f, 0.f, 0.f, 0.f, 0.f, 0.f, 0.f};
    int j = start;
    for (; j + 8 <= end; j += 8) {
        int e0 = v_edge[j + 0], e1 = v_edge[j + 1], e2 = v_edge[j + 2], e3 = v_edge[j + 3];
        int e4 = v_edge[j + 4], e5 = v_edge[j + 5], e6 = v_edge[j + 6], e7 = v_edge[j + 7];
        uint4 y0 = Yq[(size_t)e0 * 16 + l16];
        uint4 y1 = Yq[(size_t)e1 * 16 + l16];
        uint4 y2 = Yq[(size_t)e2 * 16 + l16];
        uint4 y3 = Yq[(size_t)e3 * 16 + l16];
        uint4 y4 = Yq[(size_t)e4 * 16 + l16];
        uint4 y5 = Yq[(size_t)e5 * 16 + l16];
        uint4 y6 = Yq[(size_t)e6 * 16 + l16];
        uint4 y7 = Yq[(size_t)e7 * 16 + l16];
        accum8(acc, y0); accum8(acc, y1); accum8(acc, y2); accum8(acc, y3);
        accum8(acc, y4); accum8(acc, y5); accum8(acc, y6); accum8(acc, y7);
    }
    for (; j + 4 <= end; j += 4) {
        int e0 = v_edge[j + 0], e1 = v_edge[j + 1], e2 = v_edge[j + 2], e3 = v_edge[j + 3];
        uint4 y0 = Yq[(size_t)e0 * 16 + l16];
        uint4 y1 = Yq[(size_t)e1 * 16 + l16];
        uint4 y2 = Yq[(size_t)e2 * 16 + l16];
        uint4 y3 = Yq[(size_t)e3 * 16 + l16];
        accum8(acc, y0); accum8(acc, y1); accum8(acc, y2); accum8(acc, y3);
    }
    for (; j < end; ++j) {
        int e = v_edge[j];
        uint4 y = Yq[(size_t)e * 16 + l16];
        accum8(acc, y);
    }
    float dvn = (deg > 0) ? rsqrtf((float)deg) : 0.f;
    float4 o1, o2;
    o1.x = fmaxf(acc[0] * dvn, 0.f);
    o1.y = fmaxf(acc[1] * dvn, 0.f);
    o1.z = fmaxf(acc[2] * dvn, 0.f);
    o1.w = fmaxf(acc[3] * dvn, 0.f);
    o2.x = fmaxf(acc[4] * dvn, 0.f);
    o2.y = fmaxf(acc[5] * dvn, 0.f);
    o2.z = fmaxf(acc[6] * dvn, 0.f);
    o2.w = fmaxf(acc[7] * dvn, 0.f);
    float4* op = (float4*)(out + (size_t)v * DD + l16 * 8);
    op[0] = o1;
    op[1] = o2;
}

extern "C" void kernel_launch(void* const* d_in, const int* in_sizes, int n_in,
                              void* d_out, int out_size, void* d_ws, size_t ws_size,
                              hipStream_t stream) {
    const float* X = (const float*)d_in[0];
    const float* W = (const float*)d_in[1];
    const float* b = (const float*)d_in[2];
    const int* src = (const int*)d_in[3];
    const int* dst = (const int*)d_in[4];
    int nnz = in_sizes[3];

    char* ws = (char*)d_ws;
    size_t o = 0;
    auto take = [&](size_t bytes) -> char* {
        char* p = ws + o;
        o += (bytes + 255) & ~(size_t)255;
        return p;
    };
    int* bcur_e = (int*)take((size_t)2 * NBK * 4);  // bcur_v contiguous
    int* bcur_v = bcur_e + NBK;
    int* off_e = (int*)take((size_t)NE * 4);
    int* end_e = (int*)take((size_t)NE * 4);
    int* off_v = (int*)take((size_t)NV * 4);
    int* deg_v = (int*)take((size_t)NV * 4);
    int* e_src = (int*)take((size_t)NBE * CAPE * 4);
    unsigned short* v_edge = (unsigned short*)take((size_t)NBV * CAPV * 2);
    unsigned* pairs_e = (unsigned*)take((size_t)NBE * CAPE * 4);
    unsigned* pairs_v = (unsigned*)take((size_t)NBV * CAPV * 4);
    bf16* Y = (bf16*)take((size_t)NE * DD * 2);
    bf16* Wb = (bf16*)take((size_t)DD * DD * 2);
    bf16* Xb = (bf16*)take((size_t)NV * DD * 2);
    (void)ws_size; (void)n_in; (void)out_size;

    int nchunk = (nnz + CHUNK - 1) / CHUNK;
    int ncvt = (NV * DD / 4 + DD * DD / 4 + PTHREADS - 1) / PTHREADS;

    hipMemsetAsync(bcur_e, 0, (size_t)2 * NBK * 4, stream);
    partition_and_cvt<<<2 * nchunk + ncvt, PTHREADS, 0, stream>>>(src, dst, bcur_e, bcur_v, pairs_e, pairs_v, nnz,
                                                                  (const float4*)X, (ushort4*)Xb,
                                                                  (const float4*)W, (ushort4*)Wb);
    build_csr<<<NBE + NBV, 1024, 0, stream>>>(pairs_e, bcur_e, off_e, end_e, e_src,
                                              pairs_v, bcur_v, off_v, v_edge, deg_v);
    edge_fused<<<NE / 16, 512, 0, stream>>>((const uint4*)Xb, off_e, end_e, e_src, deg_v, Wb, b, Y);
    vertex_agg<<<(NV / 4 * 64) / 256, 256, 0, stream>>>((const uint4*)Y, off_v, deg_v, v_edge, (float*)d_out);
}